// Round 4
// baseline (811.536 us; speedup 1.0000x reference)
//
#include <hip/hip_runtime.h>
#include <utility>
#include <cstddef>
#include <cmath>

// ============================================================================
// Compile-time real-basis Wigner 3j (Clebsch-Gordan) tensors.
// Device code sees only literal constants -> fully static register indexing.
// ============================================================================
namespace cg {

struct FactTab { double f[24]; };
constexpr FactTab make_fact() {
  FactTab t{}; t.f[0] = 1.0;
  for (int i = 1; i < 24; ++i) t.f[i] = t.f[i-1] * (double)i;
  return t;
}
constexpr FactTab FT = make_fact();
constexpr double F(int n) { return FT.f[n]; }

constexpr double csqrt(double x) {
  if (x <= 0.0) return 0.0;
  double g = x > 1.0 ? x : 1.0;
  for (int i = 0; i < 200; ++i) {
    double ng = 0.5 * (g + x / g);
    if (ng >= g) break;
    g = ng;
  }
  return g;
}

struct T3 { double v[13][13][13]; };

constexpr T3 w3j_c(int l1, int l2, int l3) {
  T3 C{};
  const double tri = F(l1+l2-l3) * F(l1-l2+l3) * F(-l1+l2+l3) / F(l1+l2+l3+1);
  for (int m1 = -l1; m1 <= l1; ++m1) {
    for (int m2 = -l2; m2 <= l2; ++m2) {
      const int m3 = -m1 - m2;
      if (m3 < -l3 || m3 > l3) continue;
      const int e = l1 - l2 - m3;
      const double sign = (((e % 2) + 2) % 2) ? -1.0 : 1.0;
      const double pref = sign * csqrt(tri * F(l1+m1) * F(l1-m1) * F(l2+m2)
                                           * F(l2-m2) * F(l3+m3) * F(l3-m3));
      int t0 = 0;
      if (l2 - l3 - m1 > t0) t0 = l2 - l3 - m1;
      if (l1 - l3 + m2 > t0) t0 = l1 - l3 + m2;
      int t1 = l1 + l2 - l3;
      if (l1 - m1 < t1) t1 = l1 - m1;
      if (l2 + m2 < t1) t1 = l2 + m2;
      double s = 0.0;
      for (int t = t0; t <= t1; ++t) {
        const double term = 1.0 / (F(t) * F(l1+l2-l3-t) * F(l1-m1-t)
                                   * F(l2+m2-t) * F(l3-l2+m1+t) * F(l3-l1-m2+t));
        s += (t % 2) ? -term : term;
      }
      C.v[m1+l1][m2+l2][m3+l3] = pref * s;
    }
  }
  return C;
}

struct C2 { double re, im; };
constexpr C2 cmul(C2 a, C2 b) { return C2{a.re*b.re - a.im*b.im, a.re*b.im + a.im*b.re}; }

struct UCol { int n; int row[2]; C2 val[2]; };
constexpr UCol ucol(int l, int a) {
  UCol r{};
  const double s2 = csqrt(0.5);
  if (a == l) {
    r.n = 1; r.row[0] = l; r.val[0] = C2{1.0, 0.0};
  } else if (a > l) {
    const int m = a - l;
    const double sg = (m % 2) ? -1.0 : 1.0;
    r.n = 2;
    r.row[0] = l + m; r.val[0] = C2{sg * s2, 0.0};
    r.row[1] = l - m; r.val[1] = C2{0.0, -sg * s2};
  } else {
    const int m = l - a;
    r.n = 2;
    r.row[0] = l + m; r.val[0] = C2{s2, 0.0};
    r.row[1] = l - m; r.val[1] = C2{0.0, s2};
  }
  return r;
}

constexpr T3 to_real(const T3& Cc, int l1, int l2, int l3) {
  T3 R{};
  UCol U1[13]{}, U2[13]{}, U3[13]{};
  for (int a = 0; a < 2*l1+1; ++a) U1[a] = ucol(l1, a);
  for (int b = 0; b < 2*l2+1; ++b) U2[b] = ucol(l2, b);
  for (int c = 0; c < 2*l3+1; ++c) U3[c] = ucol(l3, c);
  for (int a = 0; a < 2*l1+1; ++a)
    for (int b = 0; b < 2*l2+1; ++b)
      for (int c = 0; c < 2*l3+1; ++c) {
        const double cv = Cc.v[a][b][c];
        if (cv == 0.0) continue;
        for (int ia = 0; ia < U1[a].n; ++ia)
          for (int jb = 0; jb < U2[b].n; ++jb)
            for (int kc = 0; kc < U3[c].n; ++kc) {
              C2 t = cmul(cmul(U1[a].val[ia], U2[b].val[jb]), U3[c].val[kc]);
              R.v[U1[a].row[ia]][U2[b].row[jb]][U3[c].row[kc]] += t.re * cv;
            }
      }
  return R;
}

struct Ent { short i, j, k; float v; };
constexpr int CAP = 1100;
template <int C> struct List { int n; Ent e[C]; };

constexpr List<CAP> make_list(const T3& R, int d1, int d2, int d3) {
  List<CAP> L{};
  for (int i = 0; i < d1; ++i)
    for (int j = 0; j < d2; ++j)
      for (int k = 0; k < d3; ++k) {
        const double v = R.v[i][j][k];
        if (v > 1e-10 || v < -1e-10) {
          L.e[L.n].i = (short)i; L.e[L.n].j = (short)j; L.e[L.n].k = (short)k;
          L.e[L.n].v = (float)v;
          L.n++;
        }
      }
  return L;
}

constexpr T3 CC444 = w3j_c(4,4,4);
constexpr T3 CC446 = w3j_c(4,4,6);
constexpr T3 CC464 = w3j_c(4,6,4);
constexpr T3 CC466 = w3j_c(4,6,6);
constexpr T3 CC644 = w3j_c(6,4,4);
constexpr T3 CC646 = w3j_c(6,4,6);
constexpr T3 CC664 = w3j_c(6,6,4);
constexpr T3 CC666 = w3j_c(6,6,6);

constexpr T3 CR444 = to_real(CC444, 4,4,4);
constexpr T3 CR446 = to_real(CC446, 4,4,6);
constexpr T3 CR464 = to_real(CC464, 4,6,4);
constexpr T3 CR466 = to_real(CC466, 4,6,6);
constexpr T3 CR644 = to_real(CC644, 6,4,4);
constexpr T3 CR646 = to_real(CC646, 6,4,6);
constexpr T3 CR664 = to_real(CC664, 6,6,4);
constexpr T3 CR666 = to_real(CC666, 6,6,6);

struct Tag444 { static constexpr List<CAP> L = make_list(CR444, 9, 9, 9);  };
struct Tag446 { static constexpr List<CAP> L = make_list(CR446, 9, 9, 13); };
struct Tag464 { static constexpr List<CAP> L = make_list(CR464, 9, 13, 9); };
struct Tag466 { static constexpr List<CAP> L = make_list(CR466, 9, 13, 13);};
struct Tag644 { static constexpr List<CAP> L = make_list(CR644, 13, 9, 9); };
struct Tag646 { static constexpr List<CAP> L = make_list(CR646, 13, 9, 13);};
struct Tag664 { static constexpr List<CAP> L = make_list(CR664, 13, 13, 9);};
struct Tag666 { static constexpr List<CAP> L = make_list(CR666, 13, 13, 13);};

template <class Tag, size_t... Es>
__device__ __forceinline__ void cg_apply_impl(const float* __restrict__ x,
                                              const float* __restrict__ y,
                                              float* __restrict__ acc,
                                              std::index_sequence<Es...>) {
  ((acc[(int)Tag::L.e[Es].k] +=
        Tag::L.e[Es].v * (x[(int)Tag::L.e[Es].i] * y[(int)Tag::L.e[Es].j])), ...);
}
template <class Tag>
__device__ __forceinline__ void cg_apply(const float* __restrict__ x,
                                         const float* __restrict__ y,
                                         float* __restrict__ acc) {
  cg_apply_impl<Tag>(x, y, acc, std::make_index_sequence<(size_t)Tag::L.n>{});
}

} // namespace cg

// 4-float vector with only 4B alignment guarantee (rows are 36/52B strided).
typedef float v4u __attribute__((ext_vector_type(4), aligned(4)));
typedef float v4a __attribute__((ext_vector_type(4), aligned(16)));

// ============================================================================
// Kernel 1: vectorized word-parallel 3x3 replicate-pad depthwise conv.
// One thread per 4 contiguous WORDS of the flat array. Interior pixels: the 9
// taps are constant word offsets (dy*W+dx)*C -> 9 unaligned-vec4 loads + FMA.
// Edge / tail words: scalar clamped fallback.
// ============================================================================
__global__ __launch_bounds__(256) void conv_kernel(
    const float* __restrict__ f4, const float* __restrict__ f6,
    const float* __restrict__ sw,
    const int* __restrict__ Hp, const int* __restrict__ Wp,
    float* __restrict__ nb4, float* __restrict__ nb6) {
  const int H = Hp[0], W = Wp[0];
  const int n = H * W;
  const int g4 = (n * 9 + 3) / 4;        // vec4 groups in f4 part
  const int g6 = (n * 13 + 3) / 4;
  const int t = blockIdx.x * 256 + threadIdx.x;
  if (t >= g4 + g6) return;

  float w[9];
#pragma unroll
  for (int q = 0; q < 9; ++q) w[q] = sw[q];

  const bool is6 = (t >= g4);
  const int C = is6 ? 13 : 9;
  const float* __restrict__ src = is6 ? f6 : f4;
  float* __restrict__ dst = is6 ? nb6 : nb4;
  const int base = (is6 ? (t - g4) : t) * 4;
  const int total = n * C;

  const int p0 = base / C;
  const int p1 = (base + 3) / C;
  const int py0 = p0 / W, px0 = p0 - py0 * W;
  const int py1 = p1 / W, px1 = p1 - py1 * W;

  const bool fast = (base + 3 < total) &&
                    (px0 >= 1) && (py0 >= 1) && (px1 <= W - 2) && (py1 <= H - 2);

  if (fast) {
    v4u acc = {0.f, 0.f, 0.f, 0.f};
#pragma unroll
    for (int dy = -1; dy <= 1; ++dy) {
#pragma unroll
      for (int dx = -1; dx <= 1; ++dx) {
        const int off = (dy * W + dx) * C;
        const v4u v = *reinterpret_cast<const v4u*>(src + base + off);
        acc += w[(dy + 1) * 3 + (dx + 1)] * v;
      }
    }
    *reinterpret_cast<v4a*>(dst + base) = (v4a)acc;   // base*4B is 16B aligned
  } else {
#pragma unroll
    for (int q = 0; q < 4; ++q) {
      const int wd = base + q;
      if (wd >= total) break;
      const int p = wd / C, ch = wd - C * p;
      const int py = p / W, px = p - py * W;
      float acc = 0.0f;
#pragma unroll
      for (int dy = -1; dy <= 1; ++dy) {
        int yy = py + dy; yy = yy < 0 ? 0 : (yy >= H ? H - 1 : yy);
#pragma unroll
        for (int dx = -1; dx <= 1; ++dx) {
          int xx = px + dx; xx = xx < 0 ? 0 : (xx >= W ? W - 1 : xx);
          acc += w[(dy + 1) * 3 + (dx + 1)] * src[(size_t)(yy * W + xx) * C + ch];
        }
      }
      dst[wd] = acc;
    }
  }
}

// ============================================================================
// Kernel 2: role-split CG contraction. Block = 256 threads covering 128
// pixels twice: tid<128 -> A4-combine outputs (t4, 36 flats),
// tid>=128 -> A6-combine outputs (t6, 52 flats) for the SAME pixels
// (loads hit L1). Per-k combine folded into immediate scalar stores ->
// no o-row staging arrays -> small live set -> 4 waves/SIMD.
// ============================================================================
__global__ __launch_bounds__(256, 4) void cgc_kernel(
    const float* __restrict__ f4, const float* __restrict__ f6,
    const float* __restrict__ nb4, const float* __restrict__ nb6,
    const float* __restrict__ tpw,
    const int* __restrict__ Hp, const int* __restrict__ Wp,
    float* __restrict__ out) {
  const int H = Hp[0], W = Wp[0];
  const int n = H * W;
  const int tid = threadIdx.x;
  const bool role6 = tid >= 128;
  const int p = blockIdx.x * 128 + (tid & 127);
  if (p >= n) return;

  // ---- inputs: 12 vec4 + 4 scalar loads (44 floats) ----
  float x4[9], x6[13], y4[9], y6[13];
  {
    const float* a = f4 + (size_t)p * 9;
    v4u v0 = *reinterpret_cast<const v4u*>(a);
    v4u v1 = *reinterpret_cast<const v4u*>(a + 4);
#pragma unroll
    for (int c = 0; c < 4; ++c) { x4[c] = v0[c]; x4[c+4] = v1[c]; }
    x4[8] = a[8];
    const float* b = f6 + (size_t)p * 13;
    v4u u0 = *reinterpret_cast<const v4u*>(b);
    v4u u1 = *reinterpret_cast<const v4u*>(b + 4);
    v4u u2 = *reinterpret_cast<const v4u*>(b + 8);
#pragma unroll
    for (int c = 0; c < 4; ++c) { x6[c] = u0[c]; x6[c+4] = u1[c]; x6[c+8] = u2[c]; }
    x6[12] = b[12];
    const float* cc = nb4 + (size_t)p * 9;
    v4u w0 = *reinterpret_cast<const v4u*>(cc);
    v4u w1 = *reinterpret_cast<const v4u*>(cc + 4);
#pragma unroll
    for (int c = 0; c < 4; ++c) { y4[c] = w0[c]; y4[c+4] = w1[c]; }
    y4[8] = cc[8];
    const float* d = nb6 + (size_t)p * 13;
    v4u z0 = *reinterpret_cast<const v4u*>(d);
    v4u z1 = *reinterpret_cast<const v4u*>(d + 4);
    v4u z2 = *reinterpret_cast<const v4u*>(d + 8);
#pragma unroll
    for (int c = 0; c < 4; ++c) { y6[c] = z0[c]; y6[c+4] = z1[c]; y6[c+8] = z2[c]; }
    y6[12] = d[12];
  }

  float* __restrict__ o4p = out + (size_t)p * 36;
  float* __restrict__ o6p = out + (size_t)n * 36 + (size_t)p * 52;

  if (!role6) {
    // ---- out4 role: t4[path][9] ----
    float t0[9], t1[9], t2[9], t3[9];
#pragma unroll
    for (int k = 0; k < 9; ++k) { t0[k] = t1[k] = t2[k] = t3[k] = 0.0f; }
    cg::cg_apply<cg::Tag444>(x4, y4, t0);
    cg::cg_apply<cg::Tag464>(x4, y6, t1);
    cg::cg_apply<cg::Tag644>(x6, y4, t2);
    cg::cg_apply<cg::Tag664>(x6, y6, t3);

    const float A4 = 1.5f;  // sqrt(9/4)
#pragma unroll
    for (int c = 0; c < 4; ++c) {
      const float w0 = tpw[c * 8 + 0], w1 = tpw[c * 8 + 1];
      const float w2 = tpw[c * 8 + 2], w3 = tpw[c * 8 + 3];
#pragma unroll
      for (int k = 0; k < 9; ++k) {
        const int flat = c * 22 + k;
        float v = A4 * (w0 * t0[k] + w1 * t1[k] + w2 * t2[k] + w3 * t3[k]);
        if (flat < 36) { v += x4[flat % 9];        o4p[flat] = v; }
        else           { v += x6[(flat - 36) % 13]; o6p[flat - 36] = v; }
      }
    }
  } else {
    // ---- out6 role: t6[path][13] ----
    float s0[13], s1[13], s2[13], s3[13];
#pragma unroll
    for (int k = 0; k < 13; ++k) { s0[k] = s1[k] = s2[k] = s3[k] = 0.0f; }
    cg::cg_apply<cg::Tag446>(x4, y4, s0);
    cg::cg_apply<cg::Tag466>(x4, y6, s1);
    cg::cg_apply<cg::Tag646>(x6, y4, s2);
    cg::cg_apply<cg::Tag666>(x6, y6, s3);

    const float A6 = 1.8027756377319946f;  // sqrt(13/4)
#pragma unroll
    for (int c = 0; c < 4; ++c) {
      const float w0 = tpw[c * 8 + 4], w1 = tpw[c * 8 + 5];
      const float w2 = tpw[c * 8 + 6], w3 = tpw[c * 8 + 7];
#pragma unroll
      for (int k = 0; k < 13; ++k) {
        const int flat = c * 22 + 9 + k;
        float v = A6 * (w0 * s0[k] + w1 * s1[k] + w2 * s2[k] + w3 * s3[k]);
        if (flat < 36) { v += x4[flat % 9];        o4p[flat] = v; }
        else           { v += x6[(flat - 36) % 13]; o6p[flat - 36] = v; }
      }
    }
  }
}

// ============================================================================
// Fallback: fused single kernel (round-1 structure), used only if d_ws is too
// small for the nb intermediate. Known-correct.
// ============================================================================
__global__ __launch_bounds__(256) void fused_kernel(
    const float* __restrict__ f4, const float* __restrict__ f6,
    const float* __restrict__ sw, const float* __restrict__ tpw,
    const int* __restrict__ Hp, const int* __restrict__ Wp,
    float* __restrict__ out) {
  const int H = Hp[0], W = Wp[0];
  const int n = H * W;
  const int p = blockIdx.x * 256 + threadIdx.x;
  if (p >= n) return;
  const int py = p / W;
  const int px = p - py * W;

  float x4[9], x6[13];
  {
    const float* b4 = f4 + (size_t)p * 9;
#pragma unroll
    for (int c = 0; c < 9; ++c) x4[c] = b4[c];
    const float* b6 = f6 + (size_t)p * 13;
#pragma unroll
    for (int c = 0; c < 13; ++c) x6[c] = b6[c];
  }
  float w[9];
#pragma unroll
  for (int t = 0; t < 9; ++t) w[t] = sw[t];

  float y4[9], y6[13];
#pragma unroll
  for (int c = 0; c < 9; ++c) y4[c] = w[4] * x4[c];
#pragma unroll
  for (int c = 0; c < 13; ++c) y6[c] = w[4] * x6[c];
#pragma unroll
  for (int dy = -1; dy <= 1; ++dy) {
#pragma unroll
    for (int dx = -1; dx <= 1; ++dx) {
      if (dy == 0 && dx == 0) continue;
      int yy = py + dy; yy = yy < 0 ? 0 : (yy >= H ? H - 1 : yy);
      int xx = px + dx; xx = xx < 0 ? 0 : (xx >= W ? W - 1 : xx);
      const int q = yy * W + xx;
      const float wt = w[(dy + 1) * 3 + (dx + 1)];
      const float* b4 = f4 + (size_t)q * 9;
#pragma unroll
      for (int c = 0; c < 9; ++c) y4[c] += wt * b4[c];
      const float* b6 = f6 + (size_t)q * 13;
#pragma unroll
      for (int c = 0; c < 13; ++c) y6[c] += wt * b6[c];
    }
  }

  float t4[4][9];
  float t6[4][13];
#pragma unroll
  for (int pth = 0; pth < 4; ++pth) {
#pragma unroll
    for (int k = 0; k < 9; ++k) t4[pth][k] = 0.0f;
#pragma unroll
    for (int k = 0; k < 13; ++k) t6[pth][k] = 0.0f;
  }
  cg::cg_apply<cg::Tag444>(x4, y4, t4[0]);
  cg::cg_apply<cg::Tag446>(x4, y4, t6[0]);
  cg::cg_apply<cg::Tag464>(x4, y6, t4[1]);
  cg::cg_apply<cg::Tag466>(x4, y6, t6[1]);
  cg::cg_apply<cg::Tag644>(x6, y4, t4[2]);
  cg::cg_apply<cg::Tag646>(x6, y4, t6[2]);
  cg::cg_apply<cg::Tag664>(x6, y6, t4[3]);
  cg::cg_apply<cg::Tag666>(x6, y6, t6[3]);

  const float A4 = 1.5f;
  const float A6 = 1.8027756377319946f;
  float* __restrict__ o4p = out + (size_t)p * 36;
  float* __restrict__ o6p = out + (size_t)n * 36 + (size_t)p * 52;
#pragma unroll
  for (int c = 0; c < 4; ++c) {
    const float w40 = tpw[c * 8 + 0], w41 = tpw[c * 8 + 1];
    const float w42 = tpw[c * 8 + 2], w43 = tpw[c * 8 + 3];
    const float w60 = tpw[c * 8 + 4], w61 = tpw[c * 8 + 5];
    const float w62 = tpw[c * 8 + 6], w63 = tpw[c * 8 + 7];
#pragma unroll
    for (int k = 0; k < 9; ++k) {
      float v = A4 * (w40 * t4[0][k] + w41 * t4[1][k] +
                      w42 * t4[2][k] + w43 * t4[3][k]);
      const int flat = c * 22 + k;
      if (flat < 36) { v += x4[flat % 9];        o4p[flat] = v; }
      else           { v += x6[(flat - 36) % 13]; o6p[flat - 36] = v; }
    }
#pragma unroll
    for (int k = 0; k < 13; ++k) {
      float v = A6 * (w60 * t6[0][k] + w61 * t6[1][k] +
                      w62 * t6[2][k] + w63 * t6[3][k]);
      const int flat = c * 22 + 9 + k;
      if (flat < 36) { v += x4[flat % 9];        o4p[flat] = v; }
      else           { v += x6[(flat - 36) % 13]; o6p[flat - 36] = v; }
    }
  }
}

extern "C" void kernel_launch(void* const* d_in, const int* in_sizes, int n_in,
                              void* d_out, int out_size, void* d_ws, size_t ws_size,
                              hipStream_t stream) {
  const float* f4  = (const float*)d_in[0];
  const float* f6  = (const float*)d_in[1];
  const float* sw  = (const float*)d_in[2];
  const float* tpw = (const float*)d_in[3];
  const int*   Hp  = (const int*)d_in[4];
  const int*   Wp  = (const int*)d_in[5];
  float* out = (float*)d_out;

  const int n = in_sizes[0] / 9;  // H*W
  const size_t need = (size_t)n * 22 * sizeof(float);

  if (ws_size >= need) {
    float* nb4 = (float*)d_ws;
    float* nb6 = nb4 + (size_t)n * 9;
    const int g4 = (n * 9 + 3) / 4;
    const int g6 = (n * 13 + 3) / 4;
    const int convBlocks = (g4 + g6 + 255) / 256;
    conv_kernel<<<dim3(convBlocks), dim3(256), 0, stream>>>(
        f4, f6, sw, Hp, Wp, nb4, nb6);
    const int cgBlocks = (n + 127) / 128;
    cgc_kernel<<<dim3(cgBlocks), dim3(256), 0, stream>>>(
        f4, f6, nb4, nb6, tpw, Hp, Wp, out);
  } else {
    const int blocks = (n + 255) / 256;
    fused_kernel<<<dim3(blocks), dim3(256), 0, stream>>>(
        f4, f6, sw, tpw, Hp, Wp, out);
  }
}

// Round 6
// 376.794 us; speedup vs baseline: 2.1538x; 2.1538x over previous
//
#include <hip/hip_runtime.h>
#include <utility>
#include <cstddef>
#include <cmath>

// ============================================================================
// Compile-time real-basis Wigner 3j (Clebsch-Gordan) tensors.
// Device code sees only literal constants -> fully static register indexing.
// ============================================================================
namespace cg {

struct FactTab { double f[24]; };
constexpr FactTab make_fact() {
  FactTab t{}; t.f[0] = 1.0;
  for (int i = 1; i < 24; ++i) t.f[i] = t.f[i-1] * (double)i;
  return t;
}
constexpr FactTab FT = make_fact();
constexpr double F(int n) { return FT.f[n]; }

constexpr double csqrt(double x) {
  if (x <= 0.0) return 0.0;
  double g = x > 1.0 ? x : 1.0;
  for (int i = 0; i < 200; ++i) {
    double ng = 0.5 * (g + x / g);
    if (ng >= g) break;
    g = ng;
  }
  return g;
}

struct T3 { double v[13][13][13]; };

constexpr T3 w3j_c(int l1, int l2, int l3) {
  T3 C{};
  const double tri = F(l1+l2-l3) * F(l1-l2+l3) * F(-l1+l2+l3) / F(l1+l2+l3+1);
  for (int m1 = -l1; m1 <= l1; ++m1) {
    for (int m2 = -l2; m2 <= l2; ++m2) {
      const int m3 = -m1 - m2;
      if (m3 < -l3 || m3 > l3) continue;
      const int e = l1 - l2 - m3;
      const double sign = (((e % 2) + 2) % 2) ? -1.0 : 1.0;
      const double pref = sign * csqrt(tri * F(l1+m1) * F(l1-m1) * F(l2+m2)
                                           * F(l2-m2) * F(l3+m3) * F(l3-m3));
      int t0 = 0;
      if (l2 - l3 - m1 > t0) t0 = l2 - l3 - m1;
      if (l1 - l3 + m2 > t0) t0 = l1 - l3 + m2;
      int t1 = l1 + l2 - l3;
      if (l1 - m1 < t1) t1 = l1 - m1;
      if (l2 + m2 < t1) t1 = l2 + m2;
      double s = 0.0;
      for (int t = t0; t <= t1; ++t) {
        const double term = 1.0 / (F(t) * F(l1+l2-l3-t) * F(l1-m1-t)
                                   * F(l2+m2-t) * F(l3-l2+m1+t) * F(l3-l1-m2+t));
        s += (t % 2) ? -term : term;
      }
      C.v[m1+l1][m2+l2][m3+l3] = pref * s;
    }
  }
  return C;
}

struct C2 { double re, im; };
constexpr C2 cmul(C2 a, C2 b) { return C2{a.re*b.re - a.im*b.im, a.re*b.im + a.im*b.re}; }

struct UCol { int n; int row[2]; C2 val[2]; };
constexpr UCol ucol(int l, int a) {
  UCol r{};
  const double s2 = csqrt(0.5);
  if (a == l) {
    r.n = 1; r.row[0] = l; r.val[0] = C2{1.0, 0.0};
  } else if (a > l) {
    const int m = a - l;
    const double sg = (m % 2) ? -1.0 : 1.0;
    r.n = 2;
    r.row[0] = l + m; r.val[0] = C2{sg * s2, 0.0};
    r.row[1] = l - m; r.val[1] = C2{0.0, -sg * s2};
  } else {
    const int m = l - a;
    r.n = 2;
    r.row[0] = l + m; r.val[0] = C2{s2, 0.0};
    r.row[1] = l - m; r.val[1] = C2{0.0, s2};
  }
  return r;
}

constexpr T3 to_real(const T3& Cc, int l1, int l2, int l3) {
  T3 R{};
  UCol U1[13]{}, U2[13]{}, U3[13]{};
  for (int a = 0; a < 2*l1+1; ++a) U1[a] = ucol(l1, a);
  for (int b = 0; b < 2*l2+1; ++b) U2[b] = ucol(l2, b);
  for (int c = 0; c < 2*l3+1; ++c) U3[c] = ucol(l3, c);
  for (int a = 0; a < 2*l1+1; ++a)
    for (int b = 0; b < 2*l2+1; ++b)
      for (int c = 0; c < 2*l3+1; ++c) {
        const double cv = Cc.v[a][b][c];
        if (cv == 0.0) continue;
        for (int ia = 0; ia < U1[a].n; ++ia)
          for (int jb = 0; jb < U2[b].n; ++jb)
            for (int kc = 0; kc < U3[c].n; ++kc) {
              C2 t = cmul(cmul(U1[a].val[ia], U2[b].val[jb]), U3[c].val[kc]);
              R.v[U1[a].row[ia]][U2[b].row[jb]][U3[c].row[kc]] += t.re * cv;
            }
      }
  return R;
}

struct Ent { short i, j, k; float v; };
constexpr int CAP = 1100;
template <int C> struct List { int n; Ent e[C]; };

constexpr List<CAP> make_list(const T3& R, int d1, int d2, int d3) {
  List<CAP> L{};
  for (int i = 0; i < d1; ++i)
    for (int j = 0; j < d2; ++j)
      for (int k = 0; k < d3; ++k) {
        const double v = R.v[i][j][k];
        if (v > 1e-10 || v < -1e-10) {
          L.e[L.n].i = (short)i; L.e[L.n].j = (short)j; L.e[L.n].k = (short)k;
          L.e[L.n].v = (float)v;
          L.n++;
        }
      }
  return L;
}

constexpr T3 CC444 = w3j_c(4,4,4);
constexpr T3 CC446 = w3j_c(4,4,6);
constexpr T3 CC464 = w3j_c(4,6,4);
constexpr T3 CC466 = w3j_c(4,6,6);
constexpr T3 CC644 = w3j_c(6,4,4);
constexpr T3 CC646 = w3j_c(6,4,6);
constexpr T3 CC664 = w3j_c(6,6,4);
constexpr T3 CC666 = w3j_c(6,6,6);

constexpr T3 CR444 = to_real(CC444, 4,4,4);
constexpr T3 CR446 = to_real(CC446, 4,4,6);
constexpr T3 CR464 = to_real(CC464, 4,6,4);
constexpr T3 CR466 = to_real(CC466, 4,6,6);
constexpr T3 CR644 = to_real(CC644, 6,4,4);
constexpr T3 CR646 = to_real(CC646, 6,4,6);
constexpr T3 CR664 = to_real(CC664, 6,6,4);
constexpr T3 CR666 = to_real(CC666, 6,6,6);

struct Tag444 { static constexpr List<CAP> L = make_list(CR444, 9, 9, 9);  };
struct Tag446 { static constexpr List<CAP> L = make_list(CR446, 9, 9, 13); };
struct Tag464 { static constexpr List<CAP> L = make_list(CR464, 9, 13, 9); };
struct Tag466 { static constexpr List<CAP> L = make_list(CR466, 9, 13, 13);};
struct Tag644 { static constexpr List<CAP> L = make_list(CR644, 13, 9, 9); };
struct Tag646 { static constexpr List<CAP> L = make_list(CR646, 13, 9, 13);};
struct Tag664 { static constexpr List<CAP> L = make_list(CR664, 13, 13, 9);};
struct Tag666 { static constexpr List<CAP> L = make_list(CR666, 13, 13, 13);};

template <class Tag, size_t... Es>
__device__ __forceinline__ void cg_apply_impl(const float* __restrict__ x,
                                              const float* __restrict__ y,
                                              float* __restrict__ acc,
                                              std::index_sequence<Es...>) {
  ((acc[(int)Tag::L.e[Es].k] +=
        Tag::L.e[Es].v * (x[(int)Tag::L.e[Es].i] * y[(int)Tag::L.e[Es].j])), ...);
}
template <class Tag>
__device__ __forceinline__ void cg_apply(const float* __restrict__ x,
                                         const float* __restrict__ y,
                                         float* __restrict__ acc) {
  cg_apply_impl<Tag>(x, y, acc, std::make_index_sequence<(size_t)Tag::L.n>{});
}

} // namespace cg

// 4-float vector with only 4B alignment guarantee (rows are 36/52B strided).
typedef float v4u __attribute__((ext_vector_type(4), aligned(4)));

// ============================================================================
// Single fused kernel, role-split. No workspace, no LDS, no inter-kernel
// dependency (round 5's post-timing divergence implicated the d_ws handoff
// between conv and cgc under graph replay).
//
// Block = 256 threads covering 128 pixels twice:
//   tid <  128 -> A4-combine outputs (t4 paths, 36 accumulators)
//   tid >= 128 -> A6-combine outputs (t6 paths, 52 accumulators)
// Both roles redundantly compute the 3x3 clamped neighbor sum (vec4 loads,
// ~400 extra FMA) -- cheap vs halving the CG work + accumulator live-set.
// Role boundary is wave-aligned -> no intra-wave divergence.
// Natural register allocation (forcing occupancy spilled 1.5GB in round 4).
// ============================================================================
__global__ __launch_bounds__(256) void fused_split_kernel(
    const float* __restrict__ f4, const float* __restrict__ f6,
    const float* __restrict__ sw, const float* __restrict__ tpw,
    const int* __restrict__ Hp, const int* __restrict__ Wp,
    float* __restrict__ out) {
  const int H = Hp[0], W = Wp[0];
  const int n = H * W;
  const int tid = threadIdx.x;
  const bool role6 = tid >= 128;
  const int p = blockIdx.x * 128 + (tid & 127);
  if (p >= n) return;
  const int py = p / W;
  const int px = p - py * W;

  // ---- center features (vec4 loads; also the residual) ----
  float x4[9], x6[13];
  {
    const float* a = f4 + (size_t)p * 9;
    v4u v0 = *reinterpret_cast<const v4u*>(a);
    v4u v1 = *reinterpret_cast<const v4u*>(a + 4);
#pragma unroll
    for (int c = 0; c < 4; ++c) { x4[c] = v0[c]; x4[c + 4] = v1[c]; }
    x4[8] = a[8];
    const float* b = f6 + (size_t)p * 13;
    v4u u0 = *reinterpret_cast<const v4u*>(b);
    v4u u1 = *reinterpret_cast<const v4u*>(b + 4);
    v4u u2 = *reinterpret_cast<const v4u*>(b + 8);
#pragma unroll
    for (int c = 0; c < 4; ++c) { x6[c] = u0[c]; x6[c + 4] = u1[c]; x6[c + 8] = u2[c]; }
    x6[12] = b[12];
  }

  // ---- spatial weights (wave-uniform) ----
  float w[9];
#pragma unroll
  for (int t = 0; t < 9; ++t) w[t] = sw[t];

  // ---- 3x3 replicate-clamped weighted neighbor sum, vec4 loads ----
  float y4[9], y6[13];
#pragma unroll
  for (int c = 0; c < 9; ++c) y4[c] = w[4] * x4[c];
#pragma unroll
  for (int c = 0; c < 13; ++c) y6[c] = w[4] * x6[c];

  const int xm1 = px > 0 ? px - 1 : 0;
  const int xp1 = px < W - 1 ? px + 1 : W - 1;
  const int rm1 = (py > 0 ? py - 1 : 0) * W;
  const int r0  = py * W;
  const int rp1 = (py < H - 1 ? py + 1 : H - 1) * W;

  const int qs[8] = { rm1 + xm1, rm1 + px, rm1 + xp1,
                      r0 + xm1,             r0 + xp1,
                      rp1 + xm1, rp1 + px, rp1 + xp1 };
  const float ws[8] = { w[0], w[1], w[2], w[3], w[5], w[6], w[7], w[8] };

#pragma unroll
  for (int t = 0; t < 8; ++t) {
    const int q = qs[t];
    const float wt = ws[t];
    const float* b4 = f4 + (size_t)q * 9;
    v4u a0 = *reinterpret_cast<const v4u*>(b4);
    v4u a1 = *reinterpret_cast<const v4u*>(b4 + 4);
#pragma unroll
    for (int c = 0; c < 4; ++c) { y4[c] += wt * a0[c]; y4[c + 4] += wt * a1[c]; }
    y4[8] += wt * b4[8];
    const float* b6 = f6 + (size_t)q * 13;
    v4u c0 = *reinterpret_cast<const v4u*>(b6);
    v4u c1 = *reinterpret_cast<const v4u*>(b6 + 4);
    v4u c2 = *reinterpret_cast<const v4u*>(b6 + 8);
#pragma unroll
    for (int c = 0; c < 4; ++c) {
      y6[c] += wt * c0[c]; y6[c + 4] += wt * c1[c]; y6[c + 8] += wt * c2[c];
    }
    y6[12] += wt * b6[12];
  }

  float* __restrict__ o4p = out + (size_t)p * 36;
  float* __restrict__ o6p = out + (size_t)n * 36 + (size_t)p * 52;

  if (!role6) {
    // ---- out4 role: t4[path][9], 4 CG contractions ----
    float t0[9], t1[9], t2[9], t3[9];
#pragma unroll
    for (int k = 0; k < 9; ++k) { t0[k] = t1[k] = t2[k] = t3[k] = 0.0f; }
    cg::cg_apply<cg::Tag444>(x4, y4, t0);
    cg::cg_apply<cg::Tag464>(x4, y6, t1);
    cg::cg_apply<cg::Tag644>(x6, y4, t2);
    cg::cg_apply<cg::Tag664>(x6, y6, t3);

    const float A4 = 1.5f;  // sqrt(9/4)
#pragma unroll
    for (int c = 0; c < 4; ++c) {
      const float w0 = tpw[c * 8 + 0], w1 = tpw[c * 8 + 1];
      const float w2 = tpw[c * 8 + 2], w3 = tpw[c * 8 + 3];
#pragma unroll
      for (int k = 0; k < 9; ++k) {
        const int flat = c * 22 + k;
        float v = A4 * (w0 * t0[k] + w1 * t1[k] + w2 * t2[k] + w3 * t3[k]);
        if (flat < 36) { v += x4[flat % 9];         o4p[flat] = v; }
        else           { v += x6[(flat - 36) % 13]; o6p[flat - 36] = v; }
      }
    }
  } else {
    // ---- out6 role: t6[path][13], 4 CG contractions ----
    float s0[13], s1[13], s2[13], s3[13];
#pragma unroll
    for (int k = 0; k < 13; ++k) { s0[k] = s1[k] = s2[k] = s3[k] = 0.0f; }
    cg::cg_apply<cg::Tag446>(x4, y4, s0);
    cg::cg_apply<cg::Tag466>(x4, y6, s1);
    cg::cg_apply<cg::Tag646>(x6, y4, s2);
    cg::cg_apply<cg::Tag666>(x6, y6, s3);

    const float A6 = 1.8027756377319946f;  // sqrt(13/4)
#pragma unroll
    for (int c = 0; c < 4; ++c) {
      const float w0 = tpw[c * 8 + 4], w1 = tpw[c * 8 + 5];
      const float w2 = tpw[c * 8 + 6], w3 = tpw[c * 8 + 7];
#pragma unroll
      for (int k = 0; k < 13; ++k) {
        const int flat = c * 22 + 9 + k;
        float v = A6 * (w0 * s0[k] + w1 * s1[k] + w2 * s2[k] + w3 * s3[k]);
        if (flat < 36) { v += x4[flat % 9];         o4p[flat] = v; }
        else           { v += x6[(flat - 36) % 13]; o6p[flat - 36] = v; }
      }
    }
  }
}

extern "C" void kernel_launch(void* const* d_in, const int* in_sizes, int n_in,
                              void* d_out, int out_size, void* d_ws, size_t ws_size,
                              hipStream_t stream) {
  const float* f4  = (const float*)d_in[0];
  const float* f6  = (const float*)d_in[1];
  const float* sw  = (const float*)d_in[2];
  const float* tpw = (const float*)d_in[3];
  const int*   Hp  = (const int*)d_in[4];
  const int*   Wp  = (const int*)d_in[5];
  float* out = (float*)d_out;

  const int n = in_sizes[0] / 9;              // H*W
  const int blocks = (n + 127) / 128;         // 128 pixels per 256-thread block
  fused_split_kernel<<<dim3(blocks), dim3(256), 0, stream>>>(
      f4, f6, sw, tpw, Hp, Wp, out);
}